// Round 10
// baseline (212.699 us; speedup 1.0000x reference)
//
#include <hip/hip_runtime.h>
#include <hip/hip_bf16.h>

// Problem: B,W,H,L = 2,32,32,32 -> N=65536 voxels; D=512, E=64 heads, V=16.
// Round-21: five null results + Little's-law arithmetic (3.4 GB/s/CU ==
// exactly N_waves x one-serial-line-in-flight) say NO variant ever achieved
// memory-level parallelism: VGPR-staged pipelines die by sinking (R12),
// spill (R15), or scratch-allocated staging arrays (suspected R16/R19/R20,
// rule #20 — never falsified because the kernel left the top-5). This round
// removes RA from the equation: global_load_lds DMA (no dest VGPRs ->
// uncancelable, unspillable, depth explicit in vmcnt), R11-proven layout,
// with R11's one flaw fixed: double-buffered 8KB rounds + counted inline-asm
// s_waitcnt vmcnt(8) (+sched_barrier per rule 18) instead of vmcnt(0)
// drains. One exposed latency per tile, 8-16 KB/wave in flight by
// construction. LDS 89 KB -> 1 block/CU, 4 waves: 32 KB/CU in flight >>
// Little's-law need. Row addrs hoisted once per tile (8 shfls, not 32).
#define DDIM 512
#define VDIM 16
#define EHEADS 64
#define NVOX 65536
#define QPERH 8
#define SLICE (NVOX / QPERH)          // 8192 voxels per block slice
#define NBLOCKS (EHEADS * QPERH)      // 512 blocks
#define WRANGE (SLICE / 4)            // 2048 voxels per wave
#define WCAP 512                      // per-wave list cap (mean ~32, 43 sigma)
#define KSTEPS 16                     // K=32 MFMA steps
#define GSTEPS 4                      // k-steps per 8KB staging round
#define NG (KSTEPS / GSTEPS)          // 4 rounds per tile

typedef __bf16  bf16x8  __attribute__((ext_vector_type(8)));
typedef float   floatx4 __attribute__((ext_vector_type(4)));
typedef __attribute__((address_space(3))) unsigned int* lds_u32p;
typedef const __attribute__((address_space(1))) unsigned int* gbl_u32p;

// Counted wait on DMA completions. "memory" clobber orders the following
// ds_reads; sched_barrier(0) stops hipcc hoisting anything above it (rule 18).
#define WAITV(N) do {                                                       \
        asm volatile("s_waitcnt vmcnt(" #N ")" ::: "memory");               \
        __builtin_amdgcn_sched_barrier(0);                                  \
    } while (0)

// Issue 8 DMA loads: round G covers all 16 rows' 512B k-window G.
// Instr j covers rows j*2+(lane>>5); dest LDS linear, src XOR-preswizzled.
#define ISSUE(BUF, G)                                                       \
    _Pragma("unroll")                                                       \
    for (int j = 0; j < 8; ++j) {                                           \
        const char* gp = (const char*)x + (size_t)(unsigned)ofs[j]          \
                       + (G) * 512;                                         \
        __builtin_amdgcn_global_load_lds((gbl_u32p)gp,                      \
            (lds_u32p)((BUF) + j * 1024), 16, 0, 0);                        \
    }

// Consume one staged round: GSTEPS k-steps of swizzled LDS read + cvt + MFMA.
#define COMP(BUF, G)                                                        \
    _Pragma("unroll")                                                       \
    for (int k = 0; k < GSTEPS; ++k) {                                      \
        const int cb = k * 8 + quad * 2;                                    \
        const floatx4 a0 = *(const floatx4*)                                \
            ((BUF) + m * 512 + (((cb)     ^ (m & 7)) << 4));                \
        const floatx4 a1 = *(const floatx4*)                                \
            ((BUF) + m * 512 + (((cb + 1) ^ (m & 7)) << 4));                \
        bf16x8 af;                                                          \
        _Pragma("unroll")                                                   \
        for (int jj = 0; jj < 4; ++jj) {                                    \
            af[jj] = (__bf16)a0[jj]; af[4 + jj] = (__bf16)a1[jj];           \
        }                                                                   \
        acc = __builtin_amdgcn_mfma_f32_16x16x32_bf16(                      \
                  af, Wfrag[((G) * GSTEPS + k) * 64 + lane], acc, 0, 0, 0); \
    }

__global__ __launch_bounds__(256) void fused_decode_kernel(
    const int*   __restrict__ btg,   // (NVOX,)
    const int*   __restrict__ b2h,   // (256,)
    const float* __restrict__ x,     // (NVOX, D)
    const float* __restrict__ Wh,    // (E, V, D)
    const float* __restrict__ bh,    // (E, V)
    float*       __restrict__ out)   // (NVOX, V)
{
    __shared__ int    lut[256];                   // 1 KB
    __shared__ bf16x8 Wfrag[KSTEPS * 64];         // 16 KB, MFMA fragment order
    __shared__ int    wlist[4][WCAP];             // 8 KB, per-wave lists
    __shared__ __align__(16) char stage[4][2][GSTEPS * 16 * 128]; // 64 KB dbuf

    const int tid  = threadIdx.x;
    const int lane = tid & 63;
    const int wv   = tid >> 6;                    // wave in block (0..3)
    const int e    = blockIdx.x >> 3;             // head
    const int q    = blockIdx.x & (QPERH - 1);    // slice
    const int m    = lane & 15;
    const int quad = lane >> 4;

    lut[tid] = b2h[tid];

    // ---- Prologue: issue W-tile AND btg loads together, then convert ------
    // Wfrag[k0*64 + ln] = W[e][ln&15][k0*32 + (ln>>4)*8 + j], j=0..7
    floatx4 w0[4], w1[4];
#pragma unroll
    for (int i = 0; i < 4; ++i) {
        const int f  = i * 256 + tid;
        const int k0 = f >> 6, ln = f & 63;
        const float* src = Wh + ((size_t)e * VDIM + (ln & 15)) * DDIM
                              + k0 * 32 + (ln >> 4) * 8;
        w0[i] = *(const floatx4*)src;
        w1[i] = *(const floatx4*)(src + 4);
    }
    const int wbase = q * SLICE + wv * WRANGE;
    int bt[WRANGE / 64];
#pragma unroll
    for (int i = 0; i < WRANGE / 64; ++i)         // 32 independent loads
        bt[i] = btg[wbase + i * 64 + lane];
    __builtin_amdgcn_sched_barrier(0);            // all 40 loads in flight

#pragma unroll
    for (int i = 0; i < 4; ++i) {                 // waits W only
        bf16x8 bf;
#pragma unroll
        for (int j = 0; j < 4; ++j) {
            bf[j] = (__bf16)w0[i][j]; bf[4 + j] = (__bf16)w1[i][j];
        }
        Wfrag[i * 256 + tid] = bf;
    }
    __syncthreads();                              // ONLY barrier in the kernel

    // ---- Per-wave atomic-free scan: ballot prefix on preloaded bt[] -------
    int cnt = 0;
#pragma unroll
    for (int i = 0; i < WRANGE / 64; ++i) {
        const bool match = (lut[bt[i]] == e);
        const unsigned long long mk = __ballot(match);
        if (match) {
            const int p = cnt + __popcll(mk & ((1ull << lane) - 1ull));
            if (p < WCAP) wlist[wv][p] = wbase + i * 64 + lane;
        }
        cnt += __popcll(mk);
    }
    if (cnt > WCAP) cnt = WCAP;

    const float bv = bh[e * VDIM + m];
    const int ntiles = (cnt + 15) >> 4;
    char* const stA = stage[wv][0];               // ping
    char* const stB = stage[wv][1];               // pong

    // ---- Decode: DMA double-buffer, counted vmcnt, one latency per tile ---
    for (int t = 0; t < ntiles; ++t) {
        const int rs = t * 16;
        int rm = rs + m;
        if (rm >= cnt) rm = cnt - 1;              // clamp tail (stores guarded)
        const int idx_m = wlist[wv][rm];          // lane L holds row L&15

        // Hoist per-tile DMA source offsets: instr j covers row j*2+(lane>>5),
        // 16B-col (lane&31)^(r&7) of that row's 512B window (XOR pre-swizzle).
        int ofs[8];
#pragma unroll
        for (int j = 0; j < 8; ++j) {
            const int r  = j * 2 + (lane >> 5);
            const int ir = __shfl(idx_m, r);
            const int cs = (lane & 31) ^ (r & 7);
            ofs[j] = ir * (DDIM * 4) + cs * 16;
        }

        floatx4 acc = {0.f, 0.f, 0.f, 0.f};

        ISSUE(stA, 0)                             // rounds 0,1 in flight
        ISSUE(stB, 1)
        WAITV(8);                                 // round 0 landed
        COMP(stA, 0)
        ISSUE(stA, 2)                             // overwrite consumed ping
        WAITV(8);                                 // round 1 landed
        COMP(stB, 1)
        ISSUE(stB, 3)                             // overwrite consumed pong
        WAITV(8);                                 // round 2 landed
        COMP(stA, 2)
        WAITV(0);                                 // round 3 landed
        COMP(stB, 3)

        // D: col = m (output v), row = quad*4 + r (voxel within tile)
#pragma unroll
        for (int r = 0; r < 4; ++r) {
            const int o = rs + quad * 4 + r;
            if (o < cnt)
                out[(size_t)wlist[wv][o] * VDIM + m] = acc[r] + bv;
        }
    }
}

extern "C" void kernel_launch(void* const* d_in, const int* in_sizes, int n_in,
                              void* d_out, int out_size, void* d_ws, size_t ws_size,
                              hipStream_t stream)
{
    const int*   btg = (const int*)d_in[0];
    const float* x   = (const float*)d_in[1];
    const float* Wh  = (const float*)d_in[2];
    const float* bh  = (const float*)d_in[3];
    const int*   b2h = (const int*)d_in[4];
    float*       out = (float*)d_out;
    (void)d_ws; (void)ws_size; (void)in_sizes; (void)n_in; (void)out_size;

    fused_decode_kernel<<<NBLOCKS, 256, 0, stream>>>(btg, b2h, x, Wh, bh, out);
}